// Round 10
// baseline (1355.413 us; speedup 1.0000x reference)
//
#include <hip/hip_runtime.h>
#include <hip/hip_cooperative_groups.h>

namespace cg = cooperative_groups;

#define NN 50000
#define EE 200000
#define RR 4
#define SC_TOTAL (RR * NN)        // 200000
#define NCH 391                   // scan chunks of 512 ints
#define NTILE ((NN + 63) / 64)    // 782
#define LDA 136                   // LDS row stride (ushorts)

typedef __attribute__((ext_vector_type(8))) short bf16x8;
typedef __attribute__((ext_vector_type(4))) float f32x4;

__device__ inline unsigned short f2bf(float x) {   // round-to-nearest-even
    unsigned int u = __float_as_uint(x);
    u += 0x7fffu + ((u >> 16) & 1u);
    return (unsigned short)(u >> 16);
}
__device__ inline float bflo(unsigned u) { return __uint_as_float(u << 16); }
__device__ inline float bfhi(unsigned u) { return __uint_as_float(u & 0xffff0000u); }

// ---------------------------------------------------------------------------
// gather: quarter-wave (16 lanes x 16B) per (node,etype) segment, grid-stride.
__device__ inline void gather_phase(
    const unsigned short* __restrict__ X,
    const unsigned short* __restrict__ ssrc, const int* __restrict__ off,
    unsigned short* __restrict__ agg)
{
    const int l = threadIdx.x & 15;
    const int stride = gridDim.x * 16;
    for (int seg = blockIdx.x * 16 + (threadIdx.x >> 4); seg < SC_TOTAL; seg += stride) {
        int nl = seg >> 2;
        int r  = seg & 3;
        int s = off[r * NN + nl];
        int e = off[r * NN + nl + 1];
        float a0 = 0.f, a1 = 0.f, a2 = 0.f, a3 = 0.f, a4 = 0.f, a5 = 0.f, a6 = 0.f, a7 = 0.f;
        int j = s;
        for (; j + 1 < e; j += 2) {
            int s0 = ssrc[j], s1 = ssrc[j + 1];
            uint4 u0 = *(const uint4*)&X[(size_t)s0 * 128 + l * 8];
            uint4 u1 = *(const uint4*)&X[(size_t)s1 * 128 + l * 8];
            a0 += bflo(u0.x) + bflo(u1.x); a1 += bfhi(u0.x) + bfhi(u1.x);
            a2 += bflo(u0.y) + bflo(u1.y); a3 += bfhi(u0.y) + bfhi(u1.y);
            a4 += bflo(u0.z) + bflo(u1.z); a5 += bfhi(u0.z) + bfhi(u1.z);
            a6 += bflo(u0.w) + bflo(u1.w); a7 += bfhi(u0.w) + bfhi(u1.w);
        }
        if (j < e) {
            uint4 u0 = *(const uint4*)&X[(size_t)ssrc[j] * 128 + l * 8];
            a0 += bflo(u0.x); a1 += bfhi(u0.x);
            a2 += bflo(u0.y); a3 += bfhi(u0.y);
            a4 += bflo(u0.z); a5 += bfhi(u0.z);
            a6 += bflo(u0.w); a7 += bfhi(u0.w);
        }
        float inv = (e > s) ? 1.0f / (float)(e - s) : 0.f;
        uint4 o;
        o.x = (unsigned)f2bf(a0 * inv) | ((unsigned)f2bf(a1 * inv) << 16);
        o.y = (unsigned)f2bf(a2 * inv) | ((unsigned)f2bf(a3 * inv) << 16);
        o.z = (unsigned)f2bf(a4 * inv) | ((unsigned)f2bf(a5 * inv) << 16);
        o.w = (unsigned)f2bf(a6 * inv) | ((unsigned)f2bf(a7 * inv) << 16);
        *(uint4*)&agg[(size_t)nl * 512 + r * 128 + l * 8] = o;
    }
}

// ---------------------------------------------------------------------------
// gemm: grid-stride over 64x64 tiles (NT=4). C = A[N x 512] @ WT^T + btab[mask]
template<int ON, bool RELU_BF16>
__device__ inline void gemm_phase(
    const unsigned short* __restrict__ A, const unsigned short* __restrict__ WT,
    const float* __restrict__ btab, const unsigned char* __restrict__ mask,
    void* __restrict__ Cout, unsigned short* Al, unsigned short* Wl)
{
    constexpr int CT = ON / 64;
    const int tid  = threadIdx.x;
    const int wv   = tid >> 6;
    const int lane = tid & 63;
    const int m    = lane & 15;
    const int q    = lane >> 4;

    for (int t = blockIdx.x; t < NTILE * CT; t += gridDim.x) {
        const int row0 = (t / CT) * 64;
        const int c0   = (t % CT) * 64;
        f32x4 acc[4];
        #pragma unroll
        for (int nt = 0; nt < 4; ++nt) acc[nt] = (f32x4){0.f, 0.f, 0.f, 0.f};

        for (int ks = 0; ks < 4; ++ks) {
            #pragma unroll
            for (int it = 0; it < 4; ++it) {
                int i = it * 256 + tid;
                int rr = i >> 4, ko = i & 15;
                int row = row0 + rr;
                uint4 v = make_uint4(0, 0, 0, 0);
                if (row < NN) v = *(const uint4*)&A[(size_t)row * 512 + ks * 128 + ko * 8];
                *(uint4*)&Al[rr * LDA + ko * 8] = v;
            }
            #pragma unroll
            for (int it = 0; it < 4; ++it) {
                int i = it * 256 + tid;
                int nr = i >> 4, ko = i & 15;
                *(uint4*)&Wl[nr * LDA + ko * 8] =
                    *(const uint4*)&WT[(size_t)(c0 + nr) * 512 + ks * 128 + ko * 8];
            }
            __syncthreads();

            bf16x8 afr[4];
            #pragma unroll
            for (int kq = 0; kq < 4; ++kq)
                afr[kq] = *(const bf16x8*)&Al[(wv * 16 + m) * LDA + kq * 32 + q * 8];
            #pragma unroll
            for (int nt = 0; nt < 4; ++nt) {
                #pragma unroll
                for (int kq = 0; kq < 4; ++kq) {
                    bf16x8 bfr = *(const bf16x8*)&Wl[(nt * 16 + m) * LDA + kq * 32 + q * 8];
                    acc[nt] = __builtin_amdgcn_mfma_f32_16x16x32_bf16(afr[kq], bfr, acc[nt], 0, 0, 0);
                }
            }
            __syncthreads();
        }

        int rloc[4]; int mk[4];
        #pragma unroll
        for (int rg = 0; rg < 4; ++rg) {
            rloc[rg] = row0 + wv * 16 + q * 4 + rg;
            mk[rg] = (rloc[rg] < NN) ? (int)mask[rloc[rg]] : 0;
        }
        #pragma unroll
        for (int nt = 0; nt < 4; ++nt) {
            int col = c0 + nt * 16 + m;
            #pragma unroll
            for (int rg = 0; rg < 4; ++rg) {
                if (rloc[rg] < NN) {
                    float val = acc[nt][rg] + btab[mk[rg] * ON + col];
                    if (RELU_BF16)
                        ((unsigned short*)Cout)[(size_t)rloc[rg] * ON + col] = f2bf(fmaxf(val, 0.f));
                    else
                        ((float*)Cout)[(size_t)rloc[rg] * ON + col] = val;
                }
            }
        }
    }
}

// ---------------------------------------------------------------------------
// phases [pl, ph_]: 0 prep | 1 featb+hist | 2 chunk sums | 3 scan sums |
// 4 offsets+cur | 5 fill+mask | 6 gather1 | 7 gemm1 | 8 gather2 | 9 gemm2.
// Cooperative: pl=0, ph_=9 (grid.sync between). Fallback: 10 launches pl==ph_.
__global__ __launch_bounds__(256, 4) void mega_kernel(
    const float* __restrict__ feat, const float* __restrict__ W1,
    const float* __restrict__ b1, const float* __restrict__ W2,
    const float* __restrict__ b2, const int* __restrict__ edges,
    float* __restrict__ out,
    int* __restrict__ counts, int* __restrict__ offsets, int* __restrict__ cur,
    int* __restrict__ bsum, unsigned short* __restrict__ ssrc,
    unsigned char* __restrict__ mask,
    unsigned short* __restrict__ W1T, unsigned short* __restrict__ W2T,
    float* __restrict__ btab1, float* __restrict__ btab2,
    unsigned short* __restrict__ featb, unsigned short* __restrict__ h1r,
    unsigned short* __restrict__ agg,
    int pl, int ph_)
{
    cg::grid_group grid = cg::this_grid();
    __shared__ __align__(16) char smem[64 * LDA * 2 * 2];   // 34816B: Al+Wl / scan
    unsigned short* Al = (unsigned short*)smem;
    unsigned short* Wl = (unsigned short*)(smem + 64 * LDA * 2);
    int* lred = (int*)smem;

    const int tid  = threadIdx.x;
    const int nthr = gridDim.x * 256;
    const int gtid = blockIdx.x * 256 + tid;

    for (int ph = pl; ph <= ph_; ++ph) {
        switch (ph) {
        case 0: {   // zero counts + weight/bias prep
            for (int i = gtid; i < SC_TOTAL / 4; i += nthr)
                ((int4*)counts)[i] = make_int4(0, 0, 0, 0);
            for (int i = gtid; i < 128 * 512; i += nthr) {
                int j = i >> 9, kc = i & 511, r = kc >> 7, k = kc & 127;
                W1T[i] = f2bf(W1[r * 16384 + k * 128 + j]);
            }
            for (int i = gtid; i < 64 * 512; i += nthr) {
                int j = i >> 9, kc = i & 511, r = kc >> 7, k = kc & 127;
                W2T[i] = f2bf(W2[r * 8192 + k * 64 + j]);
            }
            for (int i = gtid; i < 16 * 128; i += nthr) {
                int mm = i >> 7, c = i & 127;
                float s = 0.f;
                #pragma unroll
                for (int r = 0; r < RR; ++r) if (mm & (1 << r)) s += b1[r * 128 + c];
                btab1[i] = s;
            }
            for (int i = gtid; i < 16 * 64; i += nthr) {
                int mm = i >> 6, c = i & 63;
                float s = 0.f;
                #pragma unroll
                for (int r = 0; r < RR; ++r) if (mm & (1 << r)) s += b2[r * 64 + c];
                btab2[i] = s;
            }
        } break;
        case 1: {   // featb conversion + degree histogram (MLP=4)
            for (int i = gtid; i < NN * 128 / 4; i += nthr) {
                float4 v = ((const float4*)feat)[i];
                unsigned lo = (unsigned)f2bf(v.x) | ((unsigned)f2bf(v.y) << 16);
                unsigned hi = (unsigned)f2bf(v.z) | ((unsigned)f2bf(v.w) << 16);
                ((uint2*)featb)[i] = make_uint2(lo, hi);
            }
            for (int i0 = gtid; i0 < RR * EE; i0 += nthr * 4) {
                int key[4];
                #pragma unroll
                for (int k = 0; k < 4; ++k) {
                    int idx = i0 + k * nthr;
                    if (idx < RR * EE) {
                        int r = idx / EE, e = idx - r * EE;
                        key[k] = r * NN + edges[(size_t)r * 2 * EE + EE + e];
                    } else key[k] = -1;
                }
                #pragma unroll
                for (int k = 0; k < 4; ++k)
                    if (key[k] >= 0) atomicAdd(&counts[key[k]], 1);
            }
        } break;
        case 2: {   // per-chunk (512 counts) sums
            for (int c = blockIdx.x; c < NCH; c += gridDim.x) {
                int j0 = c * 512 + tid * 2;
                int s = 0;
                if (j0 + 1 < SC_TOTAL) { int2 v = *(const int2*)&counts[j0]; s = v.x + v.y; }
                else if (j0 < SC_TOTAL) s = counts[j0];
                lred[tid] = s; __syncthreads();
                for (int o = 128; o > 0; o >>= 1) {
                    if (tid < o) lred[tid] += lred[tid + o];
                    __syncthreads();
                }
                if (tid == 0) bsum[c] = lred[0];
                __syncthreads();
            }
        } break;
        case 3: {   // scan chunk sums (block 0)
            if (blockIdx.x == 0) {
                int i0 = 2 * tid, i1 = 2 * tid + 1;
                int v0 = (i0 < NCH) ? bsum[i0] : 0;
                int v1 = (i1 < NCH) ? bsum[i1] : 0;
                lred[tid] = v0 + v1; __syncthreads();
                for (int o = 1; o < 256; o <<= 1) {
                    int x = (tid >= o) ? lred[tid - o] : 0;
                    __syncthreads();
                    lred[tid] += x;
                    __syncthreads();
                }
                int base = tid ? lred[tid - 1] : 0;
                if (i0 < NCH) bsum[i0] = base;
                if (i1 < NCH) bsum[i1] = base + v0;
                if (tid == 0) offsets[SC_TOTAL] = RR * EE;   // sentinel
            }
        } break;
        case 4: {   // local scan -> offsets + cursors
            for (int c = blockIdx.x; c < NCH; c += gridDim.x) {
                int j0 = c * 512 + tid * 2, j1 = j0 + 1;
                int e0 = (j0 < SC_TOTAL) ? counts[j0] : 0;
                int e1 = (j1 < SC_TOTAL) ? counts[j1] : 0;
                lred[tid] = e0 + e1; __syncthreads();
                for (int o = 1; o < 256; o <<= 1) {
                    int x = (tid >= o) ? lred[tid - o] : 0;
                    __syncthreads();
                    lred[tid] += x;
                    __syncthreads();
                }
                int base = bsum[c] + (tid ? lred[tid - 1] : 0);
                if (j0 < SC_TOTAL) { offsets[j0] = base;      cur[j0] = base; }
                if (j1 < SC_TOTAL) { offsets[j1] = base + e0; cur[j1] = base + e0; }
                __syncthreads();
            }
        } break;
        case 5: {   // fill (dst-sorted ushort src, MLP=4) + deg>0 mask
            for (int i0 = gtid; i0 < RR * EE; i0 += nthr * 4) {
                int srcv[4], key[4], pos[4];
                #pragma unroll
                for (int k = 0; k < 4; ++k) {
                    int idx = i0 + k * nthr;
                    if (idx < RR * EE) {
                        int r = idx / EE, e = idx - r * EE;
                        srcv[k] = edges[(size_t)r * 2 * EE + e];
                        key[k]  = r * NN + edges[(size_t)r * 2 * EE + EE + e];
                    } else key[k] = -1;
                }
                #pragma unroll
                for (int k = 0; k < 4; ++k)
                    if (key[k] >= 0) pos[k] = atomicAdd(&cur[key[k]], 1);
                #pragma unroll
                for (int k = 0; k < 4; ++k)
                    if (key[k] >= 0) ssrc[pos[k]] = (unsigned short)srcv[k];
            }
            for (int v = gtid; v < NN; v += nthr) {
                unsigned m = 0;
                #pragma unroll
                for (int r = 0; r < RR; ++r)
                    if (offsets[r * NN + v + 1] > offsets[r * NN + v]) m |= (1u << r);
                mask[v] = (unsigned char)m;
            }
        } break;
        case 6: gather_phase(featb, ssrc, offsets, agg); break;
        case 7: gemm_phase<128, true >(agg, W1T, btab1, mask, h1r, Al, Wl); break;
        case 8: gather_phase(h1r, ssrc, offsets, agg); break;
        case 9: gemm_phase<64, false>(agg, W2T, btab2, mask, out, Al, Wl); break;
        }
        if (ph < ph_) { __threadfence(); grid.sync(); }
    }
}

// ---------------------------------------------------------------------------
extern "C" void kernel_launch(void* const* d_in, const int* in_sizes, int n_in,
                              void* d_out, int out_size, void* d_ws, size_t ws_size,
                              hipStream_t stream)
{
    const float* feat  = (const float*)d_in[0];   // [N,128]
    const float* W1    = (const float*)d_in[1];   // [R,128,128]
    const float* b1    = (const float*)d_in[2];   // [R,128]
    const float* W2    = (const float*)d_in[3];   // [R,128,64]
    const float* b2    = (const float*)d_in[4];   // [R,64]
    const int*   edges = (const int*)d_in[5];     // [R,2,E]
    float* out = (float*)d_out;                   // [N,64] fp32

    // workspace (~81 MB of 256 MiB)
    char* p = (char*)d_ws;
    auto alloc = [&](size_t bytes) { char* q = p; p += (bytes + 255) & ~(size_t)255; return q; };
    int* counts            = (int*)alloc((size_t)SC_TOTAL * 4);
    int* offsets           = (int*)alloc((size_t)(SC_TOTAL + 4) * 4);
    int* cur               = (int*)alloc((size_t)SC_TOTAL * 4);
    int* bsum              = (int*)alloc(2048);
    unsigned short* ssrc   = (unsigned short*)alloc((size_t)RR * EE * 2);
    unsigned char* mask    = (unsigned char*)alloc(NN + 64);
    unsigned short* W1T    = (unsigned short*)alloc((size_t)128 * 512 * 2);
    unsigned short* W2T    = (unsigned short*)alloc((size_t)64 * 512 * 2);
    float* btab1           = (float*)alloc((size_t)16 * 128 * 4);
    float* btab2           = (float*)alloc((size_t)16 * 64 * 4);
    unsigned short* featb  = (unsigned short*)alloc((size_t)NN * 128 * 2);   // 12.8MB
    unsigned short* h1r    = (unsigned short*)alloc((size_t)NN * 128 * 2);   // 12.8MB
    unsigned short* agg    = (unsigned short*)alloc((size_t)NN * 512 * 2);   // 51.2MB

    // cooperative grid = exactly what the runtime says is co-resident
    int perCU = 0;
    hipError_t oe = hipOccupancyMaxActiveBlocksPerMultiprocessor(
        &perCU, (const void*)mega_kernel, 256, 0);
    int numCU = 0;
    if (hipDeviceGetAttribute(&numCU, hipDeviceAttributeMultiprocessorCount, 0)
        != hipSuccess || numCU <= 0) numCU = 256;
    int coopGrid = (oe == hipSuccess && perCU > 0) ? perCU * numCU : 0;
    if (coopGrid > 2048) coopGrid = 2048;

    bool launched = false;
    if (coopGrid >= 64) {
        int lo = 0, hi = 9;
        void* args[] = {
            (void*)&feat, (void*)&W1, (void*)&b1, (void*)&W2, (void*)&b2,
            (void*)&edges, (void*)&out,
            (void*)&counts, (void*)&offsets, (void*)&cur, (void*)&bsum,
            (void*)&ssrc, (void*)&mask, (void*)&W1T, (void*)&W2T,
            (void*)&btab1, (void*)&btab2, (void*)&featb, (void*)&h1r, (void*)&agg,
            (void*)&lo, (void*)&hi
        };
        hipError_t e = hipLaunchCooperativeKernel((void*)mega_kernel,
                                                  dim3(coopGrid), dim3(256),
                                                  args, 0, stream);
        launched = (e == hipSuccess);
        if (!launched) (void)hipGetLastError();   // clear error state
    }
    if (!launched) {
        // fallback: 10 sequential launches, stream ordering = phase barrier
        for (int ph = 0; ph <= 9; ++ph) {
            mega_kernel<<<dim3(2048), dim3(256), 0, stream>>>(
                feat, W1, b1, W2, b2, edges, out,
                counts, offsets, cur, bsum, ssrc, mask,
                W1T, W2T, btab1, btab2, featb, h1r, agg, ph, ph);
        }
    }
}

// Round 11
// 300.931 us; speedup vs baseline: 4.5041x; 4.5041x over previous
//
#include <hip/hip_runtime.h>

#define NN 50000
#define EE 200000
#define RR 4
#define SC_TOTAL (RR * NN)                 // 200000
#define NB_SCAN ((SC_TOTAL + 1023) / 1024) // 196
#define NTILE ((NN + 63) / 64)             // 782
#define LDA 136   // LDS row stride (ushorts): 16B-aligned rows, <=2-way conflicts (free)

typedef __attribute__((ext_vector_type(8))) short bf16x8;
typedef __attribute__((ext_vector_type(4))) float f32x4;

__device__ inline unsigned short f2bf(float x) {   // round-to-nearest-even
    unsigned int u = __float_as_uint(x);
    u += 0x7fffu + ((u >> 16) & 1u);
    return (unsigned short)(u >> 16);
}
__device__ inline float bflo(unsigned u) { return __uint_as_float(u << 16); }
__device__ inline float bfhi(unsigned u) { return __uint_as_float(u & 0xffff0000u); }

// ---------------------------------------------------------------------------
// init (block-range partitioned): featb [0,6250) | W1T [6250,6506) |
// W2T [6506,6634) | btab1 [6634,6642) | btab2 [6642,6646) |
// counts zero [6646,6842) | desc+ticket zero [6842,6843)
__global__ __launch_bounds__(256) void init_kernel(
    const float* __restrict__ feat, unsigned short* __restrict__ featb,
    const float* __restrict__ W1, const float* __restrict__ b1,
    const float* __restrict__ W2, const float* __restrict__ b2,
    unsigned short* __restrict__ W1T, unsigned short* __restrict__ W2T,
    float* __restrict__ btab1, float* __restrict__ btab2,
    int* __restrict__ counts, unsigned long long* __restrict__ desc,
    int* __restrict__ ticket)
{
    int b = blockIdx.x, t = threadIdx.x;
    if (b < 6250) {
        int i = (b * 256 + t) * 4;
        float4 v = *(const float4*)&feat[i];
        unsigned lo = (unsigned)f2bf(v.x) | ((unsigned)f2bf(v.y) << 16);
        unsigned hi = (unsigned)f2bf(v.z) | ((unsigned)f2bf(v.w) << 16);
        *(uint2*)&featb[i] = make_uint2(lo, hi);
    } else if (b < 6506) {
        int i = (b - 6250) * 256 + t;
        int j = i >> 9, kc = i & 511, r = kc >> 7, k = kc & 127;
        W1T[i] = f2bf(W1[r * 16384 + k * 128 + j]);
    } else if (b < 6634) {
        int i = (b - 6506) * 256 + t;
        int j = i >> 9, kc = i & 511, r = kc >> 7, k = kc & 127;
        W2T[i] = f2bf(W2[r * 8192 + k * 64 + j]);
    } else if (b < 6642) {
        int i = (b - 6634) * 256 + t;
        int mm = i >> 7, c = i & 127;
        float s = 0.f;
        #pragma unroll
        for (int r = 0; r < RR; ++r) if (mm & (1 << r)) s += b1[r * 128 + c];
        btab1[i] = s;
    } else if (b < 6646) {
        int i = (b - 6642) * 256 + t;
        int mm = i >> 6, c = i & 63;
        float s = 0.f;
        #pragma unroll
        for (int r = 0; r < RR; ++r) if (mm & (1 << r)) s += b2[r * 64 + c];
        btab2[i] = s;
    } else if (b < 6842) {
        int i = ((b - 6646) * 256 + t) * 4;
        if (i < SC_TOTAL) *(int4*)&counts[i] = make_int4(0, 0, 0, 0);
    } else {
        if (t < NB_SCAN) desc[t] = 0ULL;
        if (t == 0) *ticket = 0;
    }
}

// ---------------------------------------------------------------------------
// hist: 4 edges/thread (MLP=4)
__global__ __launch_bounds__(256) void hist_kernel(
    const int* __restrict__ edges, int* __restrict__ counts)
{
    int r = blockIdx.y;
    int e0 = blockIdx.x * 1024 + threadIdx.x;
    const int* ed = edges + (size_t)r * 2 * EE + EE;
    int d[4];
    #pragma unroll
    for (int k = 0; k < 4; ++k) {
        int e = e0 + k * 256;
        d[k] = (e < EE) ? ed[e] : -1;
    }
    #pragma unroll
    for (int k = 0; k < 4; ++k)
        if (d[k] >= 0) atomicAdd(&counts[r * NN + d[k]], 1);
}

// ---------------------------------------------------------------------------
// single-dispatch exclusive scan: decoupled lookback, ticket-ordered.
// Writes offsets[0..SC_TOTAL] (sentinel) and cursor copy.
__global__ __launch_bounds__(256) void scan_kernel(
    const int* __restrict__ counts, int* __restrict__ offsets,
    int* __restrict__ cur, unsigned long long* __restrict__ desc,
    int* __restrict__ ticket)
{
    __shared__ int lred[256];
    __shared__ int sbase, svb;
    const int t = threadIdx.x;
    if (t == 0) svb = atomicAdd(ticket, 1);
    __syncthreads();
    const int vb = svb;                 // virtual block id in dispatch order
    const int i0 = vb * 1024 + t * 4;

    int e0 = 0, e1 = 0, e2 = 0, e3 = 0;
    if (i0 + 3 < SC_TOTAL) { int4 v = *(const int4*)&counts[i0]; e0 = v.x; e1 = v.y; e2 = v.z; e3 = v.w; }
    else {
        if (i0     < SC_TOTAL) e0 = counts[i0];
        if (i0 + 1 < SC_TOTAL) e1 = counts[i0 + 1];
        if (i0 + 2 < SC_TOTAL) e2 = counts[i0 + 2];
        if (i0 + 3 < SC_TOTAL) e3 = counts[i0 + 3];
    }
    lred[t] = e0 + e1 + e2 + e3;
    __syncthreads();
    for (int o = 1; o < 256; o <<= 1) {
        int x = (t >= o) ? lred[t - o] : 0;
        __syncthreads();
        lred[t] += x;
        __syncthreads();
    }
    const int total = lred[255];

    if (t == 0) {
        if (vb == 0) {
            atomicExch(&desc[0], (2ULL << 32) | (unsigned)total);
            sbase = 0;
        } else {
            atomicExch(&desc[vb], (1ULL << 32) | (unsigned)total);
            int running = 0;
            int i = vb - 1;
            while (true) {
                unsigned long long d = atomicAdd(&desc[i], 0ULL);
                unsigned st = (unsigned)(d >> 32);
                if (st == 0) continue;                  // predecessor not ready
                running += (int)(d & 0xffffffffULL);
                if (st == 2) break;                     // found inclusive prefix
                --i;
            }
            atomicExch(&desc[vb], (2ULL << 32) | (unsigned)(running + total));
            sbase = running;
        }
        if (vb == 0) offsets[SC_TOTAL] = RR * EE;       // sentinel
    }
    __syncthreads();

    int base = sbase + ((t > 0) ? lred[t - 1] : 0);
    int o0 = base, o1 = base + e0, o2 = base + e0 + e1, o3 = base + e0 + e1 + e2;
    if (i0     < SC_TOTAL) { offsets[i0]     = o0; cur[i0]     = o0; }
    if (i0 + 1 < SC_TOTAL) { offsets[i0 + 1] = o1; cur[i0 + 1] = o1; }
    if (i0 + 2 < SC_TOTAL) { offsets[i0 + 2] = o2; cur[i0 + 2] = o2; }
    if (i0 + 3 < SC_TOTAL) { offsets[i0 + 3] = o3; cur[i0 + 3] = o3; }
}

// ---------------------------------------------------------------------------
// fill (blocks [0,784): dst-sorted ushort src, MLP=4) + mask (blocks [784,833))
__global__ __launch_bounds__(256) void fill_mask_kernel(
    const int* __restrict__ edges, int* __restrict__ cur,
    unsigned short* __restrict__ ssrc, const int* __restrict__ offsets,
    unsigned char* __restrict__ mask)
{
    int b = blockIdx.x, t = threadIdx.x;
    if (b < 784) {
        int r = b / 196, c = b - r * 196;
        int e0 = c * 1024 + t;
        const int* es = edges + (size_t)r * 2 * EE;
        int src[4], dst[4], p[4];
        #pragma unroll
        for (int k = 0; k < 4; ++k) {
            int e = e0 + k * 256;
            src[k] = (e < EE) ? es[e] : 0;
            dst[k] = (e < EE) ? es[EE + e] : -1;
        }
        #pragma unroll
        for (int k = 0; k < 4; ++k)
            if (dst[k] >= 0) p[k] = atomicAdd(&cur[r * NN + dst[k]], 1);
        #pragma unroll
        for (int k = 0; k < 4; ++k)
            if (dst[k] >= 0) ssrc[p[k]] = (unsigned short)src[k];
    } else {
        int v0 = ((b - 784) * 256 + t) * 4;
        #pragma unroll
        for (int k = 0; k < 4; ++k) {
            int v = v0 + k;
            if (v < NN) {
                unsigned m = 0;
                #pragma unroll
                for (int r = 0; r < RR; ++r)
                    if (offsets[r * NN + v + 1] > offsets[r * NN + v]) m |= (1u << r);
                mask[v] = (unsigned char)m;
            }
        }
    }
}

// ---------------------------------------------------------------------------
// segment gather-mean: quarter-wave (16 lanes x uint4 = 256B row) per
// (node,etype) segment; 4 independent segment streams per wave. Full N.
__global__ __launch_bounds__(256) void gather_seg(
    const unsigned short* __restrict__ X,   // [N,128] bf16
    const unsigned short* __restrict__ ssrc, const int* __restrict__ off,
    unsigned short* __restrict__ agg)       // [N,512] bf16
{
    int seg = blockIdx.x * 16 + (threadIdx.x >> 4);
    if (seg >= SC_TOTAL) return;
    int nl = seg >> 2;
    int r  = seg & 3;
    int l  = threadIdx.x & 15;
    int s = off[r * NN + nl];
    int e = off[r * NN + nl + 1];
    float a0 = 0.f, a1 = 0.f, a2 = 0.f, a3 = 0.f, a4 = 0.f, a5 = 0.f, a6 = 0.f, a7 = 0.f;
    int j = s;
    for (; j + 1 < e; j += 2) {
        int s0 = ssrc[j], s1 = ssrc[j + 1];
        uint4 u0 = *(const uint4*)&X[(size_t)s0 * 128 + l * 8];
        uint4 u1 = *(const uint4*)&X[(size_t)s1 * 128 + l * 8];
        a0 += bflo(u0.x) + bflo(u1.x); a1 += bfhi(u0.x) + bfhi(u1.x);
        a2 += bflo(u0.y) + bflo(u1.y); a3 += bfhi(u0.y) + bfhi(u1.y);
        a4 += bflo(u0.z) + bflo(u1.z); a5 += bfhi(u0.z) + bfhi(u1.z);
        a6 += bflo(u0.w) + bflo(u1.w); a7 += bfhi(u0.w) + bfhi(u1.w);
    }
    if (j < e) {
        uint4 u0 = *(const uint4*)&X[(size_t)ssrc[j] * 128 + l * 8];
        a0 += bflo(u0.x); a1 += bfhi(u0.x);
        a2 += bflo(u0.y); a3 += bfhi(u0.y);
        a4 += bflo(u0.z); a5 += bfhi(u0.z);
        a6 += bflo(u0.w); a7 += bfhi(u0.w);
    }
    float inv = (e > s) ? 1.0f / (float)(e - s) : 0.f;
    uint4 o;
    o.x = (unsigned)f2bf(a0 * inv) | ((unsigned)f2bf(a1 * inv) << 16);
    o.y = (unsigned)f2bf(a2 * inv) | ((unsigned)f2bf(a3 * inv) << 16);
    o.z = (unsigned)f2bf(a4 * inv) | ((unsigned)f2bf(a5 * inv) << 16);
    o.w = (unsigned)f2bf(a6 * inv) | ((unsigned)f2bf(a7 * inv) << 16);
    *(uint4*)&agg[(size_t)nl * 512 + r * 128 + l * 8] = o;
}

// ---------------------------------------------------------------------------
// concat GEMM: C[N x ON] = A[N x 512]_bf16 @ WT^T + btab[mask]; 64 x ON tiles
template<int ON, bool RELU_BF16>
__global__ __launch_bounds__(256) void gemm_cat(
    const unsigned short* __restrict__ A, const unsigned short* __restrict__ WT,
    const float* __restrict__ btab, const unsigned char* __restrict__ mask,
    void* __restrict__ Cout)
{
    constexpr int NT = ON / 16;
    __shared__ __align__(16) unsigned short Al[64 * LDA];
    __shared__ __align__(16) unsigned short Wl[ON * LDA];
    const int tid  = threadIdx.x;
    const int wv   = tid >> 6;
    const int lane = tid & 63;
    const int m    = lane & 15;
    const int q    = lane >> 4;
    const int row0 = blockIdx.x * 64;

    f32x4 acc[NT];
    #pragma unroll
    for (int nt = 0; nt < NT; ++nt) acc[nt] = (f32x4){0.f, 0.f, 0.f, 0.f};

    for (int ks = 0; ks < 4; ++ks) {
        #pragma unroll
        for (int it = 0; it < 4; ++it) {
            int i = it * 256 + tid;
            int rr = i >> 4, ko = i & 15;
            int row = row0 + rr;
            uint4 v = make_uint4(0, 0, 0, 0);
            if (row < NN) v = *(const uint4*)&A[(size_t)row * 512 + ks * 128 + ko * 8];
            *(uint4*)&Al[rr * LDA + ko * 8] = v;
        }
        for (int i = tid; i < ON * 16; i += 256) {
            int nr = i >> 4, ko = i & 15;
            *(uint4*)&Wl[nr * LDA + ko * 8] =
                *(const uint4*)&WT[(size_t)nr * 512 + ks * 128 + ko * 8];
        }
        __syncthreads();

        bf16x8 afr[4];
        #pragma unroll
        for (int kq = 0; kq < 4; ++kq)
            afr[kq] = *(const bf16x8*)&Al[(wv * 16 + m) * LDA + kq * 32 + q * 8];
        #pragma unroll
        for (int nt = 0; nt < NT; ++nt) {
            #pragma unroll
            for (int kq = 0; kq < 4; ++kq) {
                bf16x8 bfr = *(const bf16x8*)&Wl[(nt * 16 + m) * LDA + kq * 32 + q * 8];
                acc[nt] = __builtin_amdgcn_mfma_f32_16x16x32_bf16(afr[kq], bfr, acc[nt], 0, 0, 0);
            }
        }
        __syncthreads();
    }

    int rloc[4]; int mk[4];
    #pragma unroll
    for (int rg = 0; rg < 4; ++rg) {
        rloc[rg] = row0 + wv * 16 + q * 4 + rg;
        mk[rg] = (rloc[rg] < NN) ? (int)mask[rloc[rg]] : 0;
    }
    #pragma unroll
    for (int nt = 0; nt < NT; ++nt) {
        int col = nt * 16 + m;
        #pragma unroll
        for (int rg = 0; rg < 4; ++rg) {
            if (rloc[rg] < NN) {
                float val = acc[nt][rg] + btab[mk[rg] * ON + col];
                if (RELU_BF16)
                    ((unsigned short*)Cout)[(size_t)rloc[rg] * ON + col] = f2bf(fmaxf(val, 0.f));
                else
                    ((float*)Cout)[(size_t)rloc[rg] * ON + col] = val;
            }
        }
    }
}

// ---------------------------------------------------------------------------
extern "C" void kernel_launch(void* const* d_in, const int* in_sizes, int n_in,
                              void* d_out, int out_size, void* d_ws, size_t ws_size,
                              hipStream_t stream)
{
    const float* feat  = (const float*)d_in[0];   // [N,128]
    const float* W1    = (const float*)d_in[1];   // [R,128,128]
    const float* b1    = (const float*)d_in[2];   // [R,128]
    const float* W2    = (const float*)d_in[3];   // [R,128,64]
    const float* b2    = (const float*)d_in[4];   // [R,64]
    const int*   edges = (const int*)d_in[5];     // [R,2,E]
    float* out = (float*)d_out;                   // [N,64] fp32

    // workspace (~82 MB of 256 MiB)
    char* p = (char*)d_ws;
    auto alloc = [&](size_t bytes) { char* q = p; p += (bytes + 255) & ~(size_t)255; return q; };
    int* counts              = (int*)alloc((size_t)SC_TOTAL * 4);
    int* offsets             = (int*)alloc((size_t)(SC_TOTAL + 4) * 4);
    int* cur                 = (int*)alloc((size_t)SC_TOTAL * 4);
    unsigned long long* desc = (unsigned long long*)alloc(NB_SCAN * 8);
    int* ticket              = (int*)alloc(256);
    unsigned short* ssrc     = (unsigned short*)alloc((size_t)RR * EE * 2);
    unsigned char* mask      = (unsigned char*)alloc(NN + 64);
    unsigned short* W1T      = (unsigned short*)alloc((size_t)128 * 512 * 2);
    unsigned short* W2T      = (unsigned short*)alloc((size_t)64 * 512 * 2);
    float* btab1             = (float*)alloc((size_t)16 * 128 * 4);
    float* btab2             = (float*)alloc((size_t)16 * 64 * 4);
    unsigned short* featb    = (unsigned short*)alloc((size_t)NN * 128 * 2);   // 12.8MB
    unsigned short* h1r      = (unsigned short*)alloc((size_t)NN * 128 * 2);   // 12.8MB
    unsigned short* agg      = (unsigned short*)alloc((size_t)NN * 512 * 2);   // 51.2MB

    // 1: featb + weight prep + zero (counts, desc, ticket)
    init_kernel<<<6843, 256, 0, stream>>>(feat, featb, W1, b1, W2, b2,
                                          W1T, W2T, btab1, btab2,
                                          counts, desc, ticket);
    // 2: degree histogram
    dim3 eg((EE + 1023) / 1024, RR);
    hist_kernel<<<eg, 256, 0, stream>>>(edges, counts);
    // 3: exclusive scan (decoupled lookback) -> offsets + cur
    scan_kernel<<<NB_SCAN, 256, 0, stream>>>(counts, offsets, cur, desc, ticket);
    // 4: dst-sorted src fill + deg>0 mask
    fill_mask_kernel<<<833, 256, 0, stream>>>(edges, cur, ssrc, offsets, mask);

    const int SEGB = SC_TOTAL / 16;   // 12500

    // 5-6: layer 1
    gather_seg<<<SEGB, 256, 0, stream>>>(featb, ssrc, offsets, agg);
    gemm_cat<128, true><<<NTILE, 256, 0, stream>>>(agg, W1T, btab1, mask, h1r);
    // 7-8: layer 2
    gather_seg<<<SEGB, 256, 0, stream>>>(h1r, ssrc, offsets, agg);
    gemm_cat<64, false><<<NTILE, 256, 0, stream>>>(agg, W2T, btab2, mask, out);
}